// Round 1
// baseline (456.662 us; speedup 1.0000x reference)
//
#include <hip/hip_runtime.h>

#define D 4096
#define RANK 8
#define BLOCK 512
#define GRID_BLOCKS 2048

// ---------------------------------------------------------------------------
// Prep: one wave. Computes Gram of hra_u columns, column inverse norms, and
// the compact-WY T matrix (lower-triangular, diag=2) such that
//   H_{r-1}...H_0 = I - V T V^T   (V = normalized columns).
// ws layout: ws[0..7] = inv_norm[i]; ws[8..71] = T row-major (8x8, zeros above diag)
// ---------------------------------------------------------------------------
__global__ __launch_bounds__(64) void hra_prep(const float* __restrict__ u,
                                               float* __restrict__ ws) {
  const int lane = threadIdx.x;
  float g[36];
#pragma unroll
  for (int k = 0; k < 36; ++k) g[k] = 0.f;

  for (int d = lane; d < D; d += 64) {
    const float4* p = (const float4*)(u + (size_t)d * RANK);
    float4 a0 = p[0];
    float4 a1 = p[1];
    float a[8] = {a0.x, a0.y, a0.z, a0.w, a1.x, a1.y, a1.z, a1.w};
    int idx = 0;
#pragma unroll
    for (int i = 0; i < 8; ++i)
#pragma unroll
      for (int j = i; j < 8; ++j)
        g[idx++] += a[i] * a[j];
  }

#pragma unroll
  for (int off = 32; off >= 1; off >>= 1) {
#pragma unroll
    for (int k = 0; k < 36; ++k)
      g[k] += __shfl_xor(g[k], off, 64);
  }

  if (lane == 0) {
    float G[8][8];
    int idx = 0;
    for (int i = 0; i < 8; ++i)
      for (int j = i; j < 8; ++j) {
        G[i][j] = g[idx];
        G[j][i] = g[idx];
        ++idx;
      }
    float invn[8];
    for (int i = 0; i < 8; ++i) invn[i] = rsqrtf(G[i][i]);
    float Gn[8][8];
    for (int i = 0; i < 8; ++i)
      for (int j = 0; j < 8; ++j) Gn[i][j] = G[i][j] * invn[i] * invn[j];
    float T[8][8];
    for (int i = 0; i < 8; ++i)
      for (int j = 0; j < 8; ++j) T[i][j] = 0.f;
    for (int k = 0; k < 8; ++k) {
      T[k][k] = 2.f;
      for (int j = 0; j < k; ++j) {
        float s = 0.f;
        for (int l = j; l < k; ++l) s += Gn[k][l] * T[l][j];
        T[k][j] = -2.f * s;
      }
    }
    for (int i = 0; i < 8; ++i) ws[i] = invn[i];
    for (int i = 0; i < 8; ++i)
      for (int j = 0; j < 8; ++j) ws[8 + i * 8 + j] = T[i][j];
  }
}

// ---------------------------------------------------------------------------
// Main: one block processes full rows (grid-stride over rows). Each thread
// owns 8 d-elements (two coalesced float4 chunks at 4t and 2048+4t) and keeps
// its normalized-V slice in registers for the block lifetime.
// Per row: c = V^T x (block reduce), w = T c, y = x - V w.
// ---------------------------------------------------------------------------
__global__ __launch_bounds__(BLOCK, 4) void hra_main(
    const float* __restrict__ x_in, const float* __restrict__ u_raw,
    const float* __restrict__ ws, float* __restrict__ y, int rows) {
  __shared__ float sT[64];
  __shared__ float s_invn[8];
  __shared__ float s_c[BLOCK / 64][8];
  __shared__ float s_w[8];

  const int t = threadIdx.x;
  const int lane = t & 63;
  const int wid = t >> 6;

  if (t < 8) s_invn[t] = ws[t];
  if (t < 64) sT[t] = ws[8 + t];
  __syncthreads();

  float invn[8];
#pragma unroll
  for (int i = 0; i < 8; ++i) invn[i] = s_invn[i];

  // Load + normalize my V slice: d = c2*2048 + 4*t + q
  float v[2][4][8];
#pragma unroll
  for (int c2 = 0; c2 < 2; ++c2) {
#pragma unroll
    for (int q = 0; q < 4; ++q) {
      const int d = c2 * 2048 + 4 * t + q;
      const float4* p = (const float4*)(u_raw + (size_t)d * RANK);
      float4 a0 = p[0];
      float4 a1 = p[1];
      v[c2][q][0] = a0.x * invn[0];
      v[c2][q][1] = a0.y * invn[1];
      v[c2][q][2] = a0.z * invn[2];
      v[c2][q][3] = a0.w * invn[3];
      v[c2][q][4] = a1.x * invn[4];
      v[c2][q][5] = a1.y * invn[5];
      v[c2][q][6] = a1.z * invn[6];
      v[c2][q][7] = a1.w * invn[7];
    }
  }

  for (int r = blockIdx.x; r < rows; r += gridDim.x) {
    const float* xr = x_in + (size_t)r * D;
    float4 xa = *(const float4*)(xr + 4 * t);
    float4 xb = *(const float4*)(xr + 2048 + 4 * t);
    float x[2][4] = {{xa.x, xa.y, xa.z, xa.w}, {xb.x, xb.y, xb.z, xb.w}};

    // partial dots c[i] = sum_d x[d] * v[d][i]
    float acc[8];
#pragma unroll
    for (int i = 0; i < 8; ++i) acc[i] = 0.f;
#pragma unroll
    for (int c2 = 0; c2 < 2; ++c2)
#pragma unroll
      for (int q = 0; q < 4; ++q)
#pragma unroll
        for (int i = 0; i < 8; ++i)
          acc[i] += x[c2][q] * v[c2][q][i];

    // wave butterfly: every lane gets the wave-wide sums
#pragma unroll
    for (int off = 32; off >= 1; off >>= 1) {
#pragma unroll
      for (int i = 0; i < 8; ++i)
        acc[i] += __shfl_xor(acc[i], off, 64);
    }
    if (lane == 0) {
#pragma unroll
      for (int i = 0; i < 8; ++i) s_c[wid][i] = acc[i];
    }
    __syncthreads();

    // 8 threads finish the reduction and apply T
    if (t < 8) {
      float cc[8];
#pragma unroll
      for (int k = 0; k < 8; ++k) {
        float s = 0.f;
#pragma unroll
        for (int w2 = 0; w2 < BLOCK / 64; ++w2) s += s_c[w2][k];
        cc[k] = s;
      }
      float wv = 0.f;
#pragma unroll
      for (int k = 0; k < 8; ++k) wv += sT[t * 8 + k] * cc[k];
      s_w[t] = wv;
    }
    __syncthreads();

    float w[8];
#pragma unroll
    for (int i = 0; i < 8; ++i) w[i] = s_w[i];

    // y = x - V w
#pragma unroll
    for (int c2 = 0; c2 < 2; ++c2) {
#pragma unroll
      for (int q = 0; q < 4; ++q) {
        float s = 0.f;
#pragma unroll
        for (int i = 0; i < 8; ++i) s += w[i] * v[c2][q][i];
        x[c2][q] -= s;
      }
    }

    float* yr = y + (size_t)r * D;
    float4 o0 = {x[0][0], x[0][1], x[0][2], x[0][3]};
    float4 o1 = {x[1][0], x[1][1], x[1][2], x[1][3]};
    *(float4*)(yr + 4 * t) = o0;
    *(float4*)(yr + 2048 + 4 * t) = o1;
    // NOTE: no extra sync needed here beyond loop-carried ones:
    // s_c rewrites (next iter, after this point) are fenced by the
    // __syncthreads() pair inside the next iteration only if readers are
    // done — readers of s_c finished before the second sync above, and
    // readers of s_w finish before the first sync of the next iteration?
    // They do NOT — so fence explicitly:
    __syncthreads();
  }
}

extern "C" void kernel_launch(void* const* d_in, const int* in_sizes, int n_in,
                              void* d_out, int out_size, void* d_ws, size_t ws_size,
                              hipStream_t stream) {
  const float* x_in = (const float*)d_in[0];
  const float* u = (const float*)d_in[1];
  float* y = (float*)d_out;
  float* ws = (float*)d_ws;

  const int rows = in_sizes[0] / D;  // 4*2048 = 8192

  hipLaunchKernelGGL(hra_prep, dim3(1), dim3(64), 0, stream, u, ws);

  const int blocks = (rows < GRID_BLOCKS) ? rows : GRID_BLOCKS;
  hipLaunchKernelGGL(hra_main, dim3(blocks), dim3(BLOCK), 0, stream,
                     x_in, u, ws, y, rows);
}

// Round 2
// 431.819 us; speedup vs baseline: 1.0575x; 1.0575x over previous
//
#include <hip/hip_runtime.h>

#define D 4096
#define RANK 8
#define BLOCK 512
#define GRID 512          // 2 blocks/CU x 256 CU: fully co-resident (persistent)
#define NW (BLOCK / 64)

typedef float f4 __attribute__((ext_vector_type(4)));

// ---------------------------------------------------------------------------
// Single fused kernel. Compact-WY: H7..H0 = I - V T V^T, V = normalized cols.
// Every block (redundantly) computes T from its register-resident u slice:
//   Gram (36 packed upper-tri) -> wave butterfly -> LDS cross-wave -> invn ->
//   T recurrence (column-parallel over 8 threads, in LDS).
// Row loop: c = V^T x (block reduce, 2 barriers), w = T c, y = x - V w.
// x loads / y stores are nontemporal so streaming doesn't evict u from L2.
// ---------------------------------------------------------------------------
__global__ __launch_bounds__(BLOCK, 4) void hra_fused(
    const float* __restrict__ x_in, const float* __restrict__ u_raw,
    float* __restrict__ y, int rows) {
  __shared__ float s_g[NW][36];
  __shared__ float s_G[36];
  __shared__ float s_Gn[64];
  __shared__ float s_T[64];
  __shared__ float s_invn[8];
  __shared__ float s_c[NW][8];
  __shared__ float s_w[8];

  const int t = threadIdx.x;
  const int lane = t & 63;
  const int wid = t >> 6;

  // ---- load raw u slice: 8 d-elements (two coalesced float4 chunks) ----
  float v[2][4][8];
#pragma unroll
  for (int c2 = 0; c2 < 2; ++c2) {
#pragma unroll
    for (int q = 0; q < 4; ++q) {
      const int d = c2 * 2048 + 4 * t + q;
      const f4* p = (const f4*)(u_raw + (size_t)d * RANK);
      f4 a0 = p[0];
      f4 a1 = p[1];
      v[c2][q][0] = a0.x; v[c2][q][1] = a0.y;
      v[c2][q][2] = a0.z; v[c2][q][3] = a0.w;
      v[c2][q][4] = a1.x; v[c2][q][5] = a1.y;
      v[c2][q][6] = a1.z; v[c2][q][7] = a1.w;
    }
  }

  // ---- Gram partials (packed upper triangle, 36 values) ----
  float g[36];
#pragma unroll
  for (int k = 0; k < 36; ++k) g[k] = 0.f;
#pragma unroll
  for (int c2 = 0; c2 < 2; ++c2) {
#pragma unroll
    for (int q = 0; q < 4; ++q) {
      int idx = 0;
#pragma unroll
      for (int i = 0; i < 8; ++i)
#pragma unroll
        for (int j = i; j < 8; ++j)
          g[idx++] += v[c2][q][i] * v[c2][q][j];
    }
  }
#pragma unroll
  for (int off = 32; off >= 1; off >>= 1) {
#pragma unroll
    for (int k = 0; k < 36; ++k)
      g[k] += __shfl_xor(g[k], off, 64);
  }
  if (lane == 0) {
#pragma unroll
    for (int k = 0; k < 36; ++k) s_g[wid][k] = g[k];
  }
  __syncthreads();

  if (t < 36) {
    float s = 0.f;
#pragma unroll
    for (int w2 = 0; w2 < NW; ++w2) s += s_g[w2][t];
    s_G[t] = s;
  }
  __syncthreads();

  if (t < 8) {
    const int dix[8] = {0, 8, 15, 21, 26, 30, 33, 35};  // packed diag indices
    s_invn[t] = rsqrtf(s_G[dix[t]]);
  }
  __syncthreads();

  if (t < 64) {
    const int i = t >> 3, j = t & 7;
    const int ii = i < j ? i : j;
    const int jj = i < j ? j : i;
    const int idx = ii * 8 - (ii * (ii - 1)) / 2 + (jj - ii);
    s_Gn[t] = s_G[idx] * s_invn[i] * s_invn[j];
  }
  __syncthreads();

  if (t < 8) {
    // column-parallel WY recurrence: T[k][j] = -2 * sum_{l=j..k-1} Gn[k][l]T[l][j]
    const int j = t;
    for (int k = 0; k < j; ++k) s_T[k * 8 + j] = 0.f;
    s_T[j * 8 + j] = 2.f;
    for (int k = j + 1; k < 8; ++k) {
      float s = 0.f;
      for (int l = j; l < k; ++l) s += s_Gn[k * 8 + l] * s_T[l * 8 + j];
      s_T[k * 8 + j] = -2.f * s;
    }
  }
  __syncthreads();

  // ---- normalize V in registers ----
  float invn[8];
#pragma unroll
  for (int i = 0; i < 8; ++i) invn[i] = s_invn[i];
#pragma unroll
  for (int c2 = 0; c2 < 2; ++c2)
#pragma unroll
    for (int q = 0; q < 4; ++q)
#pragma unroll
      for (int i = 0; i < 8; ++i) v[c2][q][i] *= invn[i];

  // ---- persistent row loop with next-row prefetch ----
  int r = blockIdx.x;
  {
    const int r0 = (r < rows) ? r : (rows - 1);
    const float* xr0 = x_in + (size_t)r0 * D;
    // initial load (nontemporal: read-once stream)
    f4 xa = __builtin_nontemporal_load((const f4*)(xr0 + 4 * t));
    f4 xb = __builtin_nontemporal_load((const f4*)(xr0 + 2048 + 4 * t));

    for (; r < rows; r += GRID) {
      float x[2][4] = {{xa.x, xa.y, xa.z, xa.w}, {xb.x, xb.y, xb.z, xb.w}};

      // partial dots c[i] = sum_d x[d] * v[d][i]
      float acc[8];
#pragma unroll
      for (int i = 0; i < 8; ++i) acc[i] = 0.f;
#pragma unroll
      for (int c2 = 0; c2 < 2; ++c2)
#pragma unroll
        for (int q = 0; q < 4; ++q)
#pragma unroll
          for (int i = 0; i < 8; ++i)
            acc[i] += x[c2][q] * v[c2][q][i];

      // prefetch next row early (completes by barrier A at the latest)
      const int rn = (r + GRID < rows) ? (r + GRID) : r;
      const float* xrn = x_in + (size_t)rn * D;
      xa = __builtin_nontemporal_load((const f4*)(xrn + 4 * t));
      xb = __builtin_nontemporal_load((const f4*)(xrn + 2048 + 4 * t));

      // wave butterfly
#pragma unroll
      for (int off = 32; off >= 1; off >>= 1) {
#pragma unroll
        for (int i = 0; i < 8; ++i)
          acc[i] += __shfl_xor(acc[i], off, 64);
      }
      if (lane == 0) {
#pragma unroll
        for (int i = 0; i < 8; ++i) s_c[wid][i] = acc[i];
      }
      __syncthreads();  // A

      if (t < 8) {
        float cc[8];
#pragma unroll
        for (int k = 0; k < 8; ++k) {
          float s = 0.f;
#pragma unroll
          for (int w2 = 0; w2 < NW; ++w2) s += s_c[w2][k];
          cc[k] = s;
        }
        float wv = 0.f;
#pragma unroll
        for (int k = 0; k < 8; ++k) wv += s_T[t * 8 + k] * cc[k];
        s_w[t] = wv;
      }
      __syncthreads();  // B

      float w[8];
#pragma unroll
      for (int i = 0; i < 8; ++i) w[i] = s_w[i];

      // y = x - V w
#pragma unroll
      for (int c2 = 0; c2 < 2; ++c2) {
#pragma unroll
        for (int q = 0; q < 4; ++q) {
          float s = 0.f;
#pragma unroll
          for (int i = 0; i < 8; ++i) s += w[i] * v[c2][q][i];
          x[c2][q] -= s;
        }
      }

      float* yr = y + (size_t)r * D;
      f4 o0 = {x[0][0], x[0][1], x[0][2], x[0][3]};
      f4 o1 = {x[1][0], x[1][1], x[1][2], x[1][3]};
      __builtin_nontemporal_store(o0, (f4*)(yr + 4 * t));
      __builtin_nontemporal_store(o1, (f4*)(yr + 2048 + 4 * t));
      // hazard analysis: s_c next-write (pre-A) vs s_c read (A..B): fenced by B.
      // s_w next-write (next A..B) vs s_w read (post-B, pre-next-A): fenced by A.
      // => exactly 2 barriers per row suffice.
    }
  }
}

extern "C" void kernel_launch(void* const* d_in, const int* in_sizes, int n_in,
                              void* d_out, int out_size, void* d_ws, size_t ws_size,
                              hipStream_t stream) {
  const float* x_in = (const float*)d_in[0];
  const float* u = (const float*)d_in[1];
  float* y = (float*)d_out;
  (void)d_ws; (void)ws_size;

  const int rows = in_sizes[0] / D;  // 4*2048 = 8192

  hipLaunchKernelGGL(hra_fused, dim3(GRID), dim3(BLOCK), 0, stream,
                     x_in, u, y, rows);
}

// Round 3
// 305.263 us; speedup vs baseline: 1.4960x; 1.4146x over previous
//
#include <hip/hip_runtime.h>

#define D 4096
#define RANK 8
#define BLOCK 1024
#define GRID 256
#define NW (BLOCK / 64)  // 16 waves

typedef float f4 __attribute__((ext_vector_type(4)));

// ---------------------------------------------------------------------------
// Compact-WY: H7..H0 = I - V T V^T (V = normalized cols of hra_u).
// One persistent block per CU (1024 thr). Each thread owns 4 contiguous
// d-elements (one float4) and keeps its normalized V slice (4x8 = 32 regs)
// in registers for the whole kernel.
// Row loop processes PAIRS of rows, software-pipelined with ONE barrier/iter:
//   iter p: dots(pair p) -> lane0 writes s_c[p&1]
//           wave0 worker: w = T c for pair p-1 (concurrent with other waves)
//           __syncthreads()
//           all: read s_w[(p-1)&1], update + store pair p-1
// ---------------------------------------------------------------------------
__global__ __launch_bounds__(BLOCK, 4) void hra_fused(
    const float* __restrict__ x_in, const float* __restrict__ u_raw,
    float* __restrict__ y, int rows) {
  __shared__ float s_g[NW][36];
  __shared__ float s_G[36];
  __shared__ float s_Gn[64];
  __shared__ float s_T[64];
  __shared__ float s_invn[8];
  __shared__ float s_c[2][2][NW][8];  // [buf][row][wave][coef]
  __shared__ float s_w[2][2][8];      // [buf][row][coef]

  const int t = threadIdx.x;
  const int lane = t & 63;
  const int wid = t >> 6;

  // ---- load raw u slice: 4 contiguous d-elements, 8 coeffs each ----
  float v[4][8];
#pragma unroll
  for (int q = 0; q < 4; ++q) {
    const int d = 4 * t + q;
    const f4* p = (const f4*)(u_raw + (size_t)d * RANK);
    f4 a0 = p[0];
    f4 a1 = p[1];
    v[q][0] = a0.x; v[q][1] = a0.y; v[q][2] = a0.z; v[q][3] = a0.w;
    v[q][4] = a1.x; v[q][5] = a1.y; v[q][6] = a1.z; v[q][7] = a1.w;
  }

  // ---- Gram partials (packed upper triangle, 36 values) ----
  {
    float g[36];
#pragma unroll
    for (int k = 0; k < 36; ++k) g[k] = 0.f;
#pragma unroll
    for (int q = 0; q < 4; ++q) {
      int idx = 0;
#pragma unroll
      for (int i = 0; i < 8; ++i)
#pragma unroll
        for (int j = i; j < 8; ++j)
          g[idx++] += v[q][i] * v[q][j];
    }
#pragma unroll
    for (int off = 32; off >= 1; off >>= 1) {
#pragma unroll
      for (int k = 0; k < 36; ++k)
        g[k] += __shfl_xor(g[k], off, 64);
    }
    if (lane == 0) {
#pragma unroll
      for (int k = 0; k < 36; ++k) s_g[wid][k] = g[k];
    }
  }
  __syncthreads();

  if (t < 36) {
    float s = 0.f;
#pragma unroll
    for (int w2 = 0; w2 < NW; ++w2) s += s_g[w2][t];
    s_G[t] = s;
  }
  __syncthreads();

  if (t < 8) {
    const int dix[8] = {0, 8, 15, 21, 26, 30, 33, 35};
    s_invn[t] = rsqrtf(s_G[dix[t]]);
  }
  __syncthreads();

  if (t < 64) {
    const int i = t >> 3, j = t & 7;
    const int ii = i < j ? i : j;
    const int jj = i < j ? j : i;
    const int idx = ii * 8 - (ii * (ii - 1)) / 2 + (jj - ii);
    s_Gn[t] = s_G[idx] * s_invn[i] * s_invn[j];
  }
  __syncthreads();

  if (t < 8) {
    // column-parallel WY recurrence
    const int j = t;
    for (int k = 0; k < j; ++k) s_T[k * 8 + j] = 0.f;
    s_T[j * 8 + j] = 2.f;
    for (int k = j + 1; k < 8; ++k) {
      float s = 0.f;
      for (int l = j; l < k; ++l) s += s_Gn[k * 8 + l] * s_T[l * 8 + j];
      s_T[k * 8 + j] = -2.f * s;
    }
  }
  __syncthreads();

  // normalize V; load worker's T row (row index (t>>2)&7 — the worker mapping)
  {
    float invn[8];
#pragma unroll
    for (int i = 0; i < 8; ++i) invn[i] = s_invn[i];
#pragma unroll
    for (int q = 0; q < 4; ++q)
#pragma unroll
      for (int i = 0; i < 8; ++i) v[q][i] *= invn[i];
  }
  float Trow[8];
#pragma unroll
  for (int k = 0; k < 8; ++k) Trow[k] = s_T[((t >> 2) & 7) * 8 + k];

  // ---- pipelined pair loop ----
  const int rpb = rows / GRID;  // 32
  const int npair = rpb / 2;    // 16
  const int base = blockIdx.x * rpb;

  f4 nxt0 = *(const f4*)(x_in + (size_t)(base + 0) * D + 4 * t);
  f4 nxt1 = *(const f4*)(x_in + (size_t)(base + 1) * D + 4 * t);
  f4 cur0, cur1, prv0, prv1;

#pragma unroll 2
  for (int p = 0; p < npair; ++p) {
    cur0 = nxt0;
    cur1 = nxt1;
    const float xc0[4] = {cur0.x, cur0.y, cur0.z, cur0.w};
    const float xc1[4] = {cur1.x, cur1.y, cur1.z, cur1.w};

    // dots for pair p
    float acc[2][8];
#pragma unroll
    for (int i = 0; i < 8; ++i) { acc[0][i] = 0.f; acc[1][i] = 0.f; }
#pragma unroll
    for (int q = 0; q < 4; ++q)
#pragma unroll
      for (int i = 0; i < 8; ++i) {
        acc[0][i] += xc0[q] * v[q][i];
        acc[1][i] += xc1[q] * v[q][i];
      }

    // prefetch pair p+1 (clamped)
    const int pn = (p + 1 < npair) ? p + 1 : p;
    nxt0 = *(const f4*)(x_in + (size_t)(base + 2 * pn) * D + 4 * t);
    nxt1 = *(const f4*)(x_in + (size_t)(base + 2 * pn + 1) * D + 4 * t);

    // butterfly (both rows)
#pragma unroll
    for (int off = 32; off >= 1; off >>= 1) {
#pragma unroll
      for (int i = 0; i < 8; ++i) {
        acc[0][i] += __shfl_xor(acc[0][i], off, 64);
        acc[1][i] += __shfl_xor(acc[1][i], off, 64);
      }
    }
    if (lane == 0) {
      f4 a0 = {acc[0][0], acc[0][1], acc[0][2], acc[0][3]};
      f4 a1 = {acc[0][4], acc[0][5], acc[0][6], acc[0][7]};
      f4 b0 = {acc[1][0], acc[1][1], acc[1][2], acc[1][3]};
      f4 b1 = {acc[1][4], acc[1][5], acc[1][6], acc[1][7]};
      *(f4*)&s_c[p & 1][0][wid][0] = a0;
      *(f4*)&s_c[p & 1][0][wid][4] = a1;
      *(f4*)&s_c[p & 1][1][wid][0] = b0;
      *(f4*)&s_c[p & 1][1][wid][4] = b1;
    }

    // worker phase (wave 0 only): w = T c for pair p-1
    if (p > 0 && t < 64) {
      const int row = t >> 5;       // 0..1
      const int j = (t >> 2) & 7;   // coef (matches Trow)
      const int s = t & 3;          // wave-slice
      const float* cb = &s_c[(p - 1) & 1][row][0][0];
      f4 cl = *(const f4*)(cb + s * 8) + *(const f4*)(cb + (s + 4) * 8) +
              *(const f4*)(cb + (s + 8) * 8) + *(const f4*)(cb + (s + 12) * 8);
      f4 ch = *(const f4*)(cb + s * 8 + 4) + *(const f4*)(cb + (s + 4) * 8 + 4) +
              *(const f4*)(cb + (s + 8) * 8 + 4) + *(const f4*)(cb + (s + 12) * 8 + 4);
      float wsum = Trow[0] * cl.x + Trow[1] * cl.y + Trow[2] * cl.z +
                   Trow[3] * cl.w + Trow[4] * ch.x + Trow[5] * ch.y +
                   Trow[6] * ch.z + Trow[7] * ch.w;
      wsum += __shfl_xor(wsum, 1, 64);
      wsum += __shfl_xor(wsum, 2, 64);
      if (s == 0) s_w[(p - 1) & 1][row][j] = wsum;
      (void)j;
    }

    __syncthreads();  // the ONLY barrier per iteration

    // update + store pair p-1
    if (p > 0) {
      float w0[8], w1[8];
#pragma unroll
      for (int i = 0; i < 8; ++i) {
        w0[i] = s_w[(p - 1) & 1][0][i];
        w1[i] = s_w[(p - 1) & 1][1][i];
      }
      float xp0[4] = {prv0.x, prv0.y, prv0.z, prv0.w};
      float xp1[4] = {prv1.x, prv1.y, prv1.z, prv1.w};
#pragma unroll
      for (int q = 0; q < 4; ++q) {
        float s0 = 0.f, s1 = 0.f;
#pragma unroll
        for (int i = 0; i < 8; ++i) {
          s0 += w0[i] * v[q][i];
          s1 += w1[i] * v[q][i];
        }
        xp0[q] -= s0;
        xp1[q] -= s1;
      }
      f4 o0 = {xp0[0], xp0[1], xp0[2], xp0[3]};
      f4 o1 = {xp1[0], xp1[1], xp1[2], xp1[3]};
      *(f4*)(y + (size_t)(base + 2 * (p - 1)) * D + 4 * t) = o0;
      *(f4*)(y + (size_t)(base + 2 * (p - 1) + 1) * D + 4 * t) = o1;
    }
    prv0 = cur0;
    prv1 = cur1;
  }

  // ---- epilogue: worker + update for the last pair ----
  {
    const int pl = npair - 1;
    if (t < 64) {
      const int row = t >> 5;
      const int j = (t >> 2) & 7;
      const int s = t & 3;
      const float* cb = &s_c[pl & 1][row][0][0];
      f4 cl = *(const f4*)(cb + s * 8) + *(const f4*)(cb + (s + 4) * 8) +
              *(const f4*)(cb + (s + 8) * 8) + *(const f4*)(cb + (s + 12) * 8);
      f4 ch = *(const f4*)(cb + s * 8 + 4) + *(const f4*)(cb + (s + 4) * 8 + 4) +
              *(const f4*)(cb + (s + 8) * 8 + 4) + *(const f4*)(cb + (s + 12) * 8 + 4);
      float wsum = Trow[0] * cl.x + Trow[1] * cl.y + Trow[2] * cl.z +
                   Trow[3] * cl.w + Trow[4] * ch.x + Trow[5] * ch.y +
                   Trow[6] * ch.z + Trow[7] * ch.w;
      wsum += __shfl_xor(wsum, 1, 64);
      wsum += __shfl_xor(wsum, 2, 64);
      if (s == 0) s_w[pl & 1][row][j] = wsum;
    }
    __syncthreads();

    float w0[8], w1[8];
#pragma unroll
    for (int i = 0; i < 8; ++i) {
      w0[i] = s_w[pl & 1][0][i];
      w1[i] = s_w[pl & 1][1][i];
    }
    float xp0[4] = {prv0.x, prv0.y, prv0.z, prv0.w};
    float xp1[4] = {prv1.x, prv1.y, prv1.z, prv1.w};
#pragma unroll
    for (int q = 0; q < 4; ++q) {
      float s0 = 0.f, s1 = 0.f;
#pragma unroll
      for (int i = 0; i < 8; ++i) {
        s0 += w0[i] * v[q][i];
        s1 += w1[i] * v[q][i];
      }
      xp0[q] -= s0;
      xp1[q] -= s1;
    }
    f4 o0 = {xp0[0], xp0[1], xp0[2], xp0[3]};
    f4 o1 = {xp1[0], xp1[1], xp1[2], xp1[3]};
    *(f4*)(y + (size_t)(base + 2 * pl) * D + 4 * t) = o0;
    *(f4*)(y + (size_t)(base + 2 * pl + 1) * D + 4 * t) = o1;
  }
}

extern "C" void kernel_launch(void* const* d_in, const int* in_sizes, int n_in,
                              void* d_out, int out_size, void* d_ws, size_t ws_size,
                              hipStream_t stream) {
  const float* x_in = (const float*)d_in[0];
  const float* u = (const float*)d_in[1];
  float* y = (float*)d_out;
  (void)d_ws; (void)ws_size;

  const int rows = in_sizes[0] / D;  // 8192

  hipLaunchKernelGGL(hra_fused, dim3(GRID), dim3(BLOCK), 0, stream,
                     x_in, u, y, rows);
}